// Round 3
// baseline (134.594 us; speedup 1.0000x reference)
//
#include <hip/hip_runtime.h>

#define NTOK 2048
#define IN_DIM 1024
#define OUT_DIM 512
#define RNK 32
#define TG_N 32
#define TGK_N 128
#define AWCOLS 4096
#define KD 4224          // 4096 affine_w cols + 128 bias-indicator cols
#define NKT 66           // KD / 64
#define SCALE_F 0.17677669529663687f
#define W2T_BLOCKS 2112  // (KD/32) * (OUT_DIM/32)

typedef __attribute__((ext_vector_type(8))) short short8;
typedef __attribute__((ext_vector_type(4))) float float4v;

__device__ __forceinline__ unsigned short f2bf(float f) {
  union { float f; unsigned int u; } c; c.f = f;
  unsigned int u = c.u;
  u += 0x7fffu + ((u >> 16) & 1u);   // round-to-nearest-even
  return (unsigned short)(u >> 16);
}

// Fused prep: blocks [0, 2112) build W2t (cast+transpose of affine_w/affine_b);
// blocks [2112, 2624) compute z + winners for 4 tokens each. Horizontal fusion
// overlaps the two phases in one dispatch.
__global__ __launch_bounds__(256) void k_prep(
    const float* __restrict__ aw, const float* __restrict__ ab,
    const float* __restrict__ x, const float* __restrict__ proj_w,
    const float* __restrict__ router_w, const float* __restrict__ router_b,
    unsigned short* __restrict__ w2t,
    unsigned short* __restrict__ zout, unsigned long long* __restrict__ wout) {
  const int t = threadIdx.x;

  if (blockIdx.x < W2T_BLOCKS) {
    __shared__ float tile[32][33];
    const int c0 = (blockIdx.x % 132) * 32, o0 = (blockIdx.x / 132) * 32;
    const int oo = t & 31, cc = t >> 5;  // cc 0..7
#pragma unroll
    for (int p = 0; p < 4; ++p) {
      int cidx = c0 + cc + p * 8;
      float v = (cidx < AWCOLS)
                    ? aw[(size_t)cidx * OUT_DIM + o0 + oo]
                    : ab[(size_t)(cidx - AWCOLS) * OUT_DIM + o0 + oo];
      tile[cc + p * 8][oo] = v;
    }
    __syncthreads();
    const int cc2 = t & 31, oo2 = t >> 5;
#pragma unroll
    for (int p = 0; p < 4; ++p) {
      int o = o0 + oo2 + p * 8;
      w2t[(size_t)o * KD + c0 + cc2] = f2bf(tile[cc2][oo2 + p * 8]);
    }
    return;
  }

  // ---- zwin: 4 tokens per block, fp32 summation order identical to R1/R2 ----
  __shared__ __align__(16) float zbuf[4][RNK];
  __shared__ float sc[4][TGK_N];
  __shared__ int winbuf[4][TG_N];
  const int tok4 = (blockIdx.x - W2T_BLOCKS) * 4;
  const int r = t >> 3, c = t & 7;
  const float4* w4 = (const float4*)(proj_w + (size_t)r * IN_DIM);
  const float4* x0 = (const float4*)(x + (size_t)tok4 * IN_DIM);
  float acc[4] = {0.f, 0.f, 0.f, 0.f};
#pragma unroll
  for (int jj = 0; jj < 32; ++jj) {
    float4 wv = w4[jj * 8 + c];
#pragma unroll
    for (int tk = 0; tk < 4; ++tk) {
      float4 xv = x0[tk * 256 + jj * 8 + c];
      acc[tk] += xv.x * wv.x + xv.y * wv.y + xv.z * wv.z + xv.w * wv.w;
    }
  }
#pragma unroll
  for (int tk = 0; tk < 4; ++tk) {
    float a = acc[tk];
    a += __shfl_xor(a, 1);
    a += __shfl_xor(a, 2);
    a += __shfl_xor(a, 4);
    if (c == 0) zbuf[tk][r] = a;
  }
  __syncthreads();

  {  // scores: thread handles cell (t&127) for tokens (t>>7) and (t>>7)+2
    const int cell = t & 127, th = t >> 7;
    const float4* rw = (const float4*)(router_w + (size_t)cell * RNK);
    float4 a[8];
#pragma unroll
    for (int j = 0; j < 8; ++j) a[j] = rw[j];
    const float rb = router_b[cell];
#pragma unroll
    for (int p = 0; p < 2; ++p) {
      const int tk = th + p * 2;
      const float4* zb = (const float4*)(&zbuf[tk][0]);
      float s = rb;
#pragma unroll
      for (int j = 0; j < 8; ++j) {
        float4 b = zb[j];
        s += a[j].x * b.x + a[j].y * b.y + a[j].z * b.z + a[j].w * b.w;
      }
      sc[tk][cell] = s;
    }
  }
  __syncthreads();

  if (t < 128) {
    const int tk = t >> 5, tg = t & 31;
    float best = sc[tk][tg * 4]; int w = 0;
#pragma unroll
    for (int k = 1; k < 4; ++k) {
      float v = sc[tk][tg * 4 + k];
      if (v < best) { best = v; w = k; }
    }
    winbuf[tk][tg] = w;
    zout[(size_t)(tok4 + tk) * RNK + tg] = f2bf(zbuf[tk][tg]);  // tg doubles as r
  }
  __syncthreads();
  if (t < 4) {
    unsigned long long w = 0ull;
    for (int g = 0; g < TG_N; ++g)
      w |= ((unsigned long long)(winbuf[t][g] & 3)) << (2 * g);
    wout[tok4 + t] = w;
  }
}

// GEMM: out = Zexp @ W2t^T, Zexp in registers (z-frag masked by winner bits),
// B-frags loaded per-lane DIRECTLY from global (L2-resident, k-contiguous).
// No LDS, no barriers; depth-2 register pipeline on B. 64Mx32N per block,
// grid 32x16 = 512 blocks (2/CU).
__global__ __launch_bounds__(256) void k_gemm(
    const unsigned short* __restrict__ z, const unsigned long long* __restrict__ win,
    const unsigned short* __restrict__ Bt, float* __restrict__ out) {
  const int bm = blockIdx.x, bn = blockIdx.y;
  const int tid = threadIdx.x;
  const int wave = tid >> 6, lane = tid & 63;
  const int l15 = lane & 15, quad = lane >> 4;
  const int mw = (wave & 1) * 32;   // wave M offset
  const int nw = (wave >> 1) * 16;  // wave N offset

  const int m0 = bm * 64 + mw + l15;
  const int m1 = m0 + 16;
  short8 z0 = *(const short8*)(z + (size_t)m0 * RNK + quad * 8);
  short8 z1 = *(const short8*)(z + (size_t)m1 * RNK + quad * 8);
  const unsigned long long w0 = win[m0], w1 = win[m1];

  // lane's B-frag base: row n = bn*32 + nw + l15, k-chunk = quad*8 (+ s*32 + kt*64)
  const unsigned short* bp = Bt + (size_t)(bn * 32 + nw + l15) * KD + quad * 8;

  float4v acc0 = {}, acc1 = {};
  short8 c0a = *(const short8*)(bp + 0);    // kt,   s=0
  short8 c0b = *(const short8*)(bp + 32);   // kt,   s=1
  short8 c1a = *(const short8*)(bp + 64);   // kt+1, s=0
  short8 c1b = *(const short8*)(bp + 96);   // kt+1, s=1

#pragma unroll 2
  for (int kt = 0; kt < NKT; ++kt) {
    const int kf = (kt + 2 < NKT) ? kt + 2 : NKT - 1;  // clamped prefetch
    short8 pa = *(const short8*)(bp + (size_t)kf * 64);
    short8 pb = *(const short8*)(bp + (size_t)kf * 64 + 32);

    if (kt < 64) {
      const int tg = kt >> 1;
      const unsigned e0 = (unsigned)(w0 >> (2 * tg)) & 3u;
      const unsigned e1 = (unsigned)(w1 >> (2 * tg)) & 3u;
      const unsigned kk0 = (unsigned)((kt & 1) << 1), kk1 = kk0 | 1u;
      short8 zz = {};
      acc0 = __builtin_amdgcn_mfma_f32_16x16x32_bf16(e0 == kk0 ? z0 : zz, c0a, acc0, 0, 0, 0);
      acc1 = __builtin_amdgcn_mfma_f32_16x16x32_bf16(e1 == kk0 ? z1 : zz, c0a, acc1, 0, 0, 0);
      acc0 = __builtin_amdgcn_mfma_f32_16x16x32_bf16(e0 == kk1 ? z0 : zz, c0b, acc0, 0, 0, 0);
      acc1 = __builtin_amdgcn_mfma_f32_16x16x32_bf16(e1 == kk1 ? z1 : zz, c0b, acc1, 0, 0, 0);
    } else {
      // bias-indicator tiles: cols 4096..4223, one-hot bf16(1.0) at winner cell
#pragma unroll
      for (int s = 0; s < 2; ++s) {
        const int tgA = (kt - 64) * 16 + s * 8 + quad * 2;  // <= 30
        union { short8 v; unsigned long long q[2]; } fa, fb;
        fa.q[0] = 0x3F80ull << (((unsigned)(w0 >> (2 * tgA)) & 3u) * 16);
        fa.q[1] = 0x3F80ull << (((unsigned)(w0 >> (2 * (tgA + 1))) & 3u) * 16);
        fb.q[0] = 0x3F80ull << (((unsigned)(w1 >> (2 * tgA)) & 3u) * 16);
        fb.q[1] = 0x3F80ull << (((unsigned)(w1 >> (2 * (tgA + 1))) & 3u) * 16);
        short8 b = s ? c0b : c0a;
        acc0 = __builtin_amdgcn_mfma_f32_16x16x32_bf16(fa.v, b, acc0, 0, 0, 0);
        acc1 = __builtin_amdgcn_mfma_f32_16x16x32_bf16(fb.v, b, acc1, 0, 0, 0);
      }
    }
    c0a = c1a; c0b = c1b; c1a = pa; c1b = pb;
  }

  // epilogue: C/D layout col = lane&15, row = quad*4 + reg
  const int col = bn * 32 + nw + l15;
#pragma unroll
  for (int tm = 0; tm < 2; ++tm) {
    float4v a = tm ? acc1 : acc0;
    const int rowb = bm * 64 + mw + tm * 16 + quad * 4;
#pragma unroll
    for (int rg = 0; rg < 4; ++rg)
      out[(size_t)(rowb + rg) * OUT_DIM + col] = a[rg] * SCALE_F;
  }
}

extern "C" void kernel_launch(void* const* d_in, const int* in_sizes, int n_in,
                              void* d_out, int out_size, void* d_ws, size_t ws_size,
                              hipStream_t stream) {
  const float* x        = (const float*)d_in[0];
  const float* proj_w   = (const float*)d_in[1];
  const float* router_w = (const float*)d_in[2];
  const float* router_b = (const float*)d_in[3];
  const float* affine_w = (const float*)d_in[4];
  const float* affine_b = (const float*)d_in[5];
  float* out = (float*)d_out;

  unsigned short* zout = (unsigned short*)d_ws;                            // 128 KB
  unsigned long long* wout = (unsigned long long*)((char*)d_ws + 131072);  // 16 KB
  unsigned short* w2t = (unsigned short*)((char*)d_ws + 147456);           // 4.33 MB

  k_prep<<<W2T_BLOCKS + NTOK / 4, 256, 0, stream>>>(
      affine_w, affine_b, x, proj_w, router_w, router_b, w2t, zout, wout);
  k_gemm<<<dim3(NTOK / 64, OUT_DIM / 32), 256, 0, stream>>>(zout, wout, w2t, out);
}

// Round 4
// 106.512 us; speedup vs baseline: 1.2637x; 1.2637x over previous
//
#include <hip/hip_runtime.h>

#define NTOK 2048
#define IN_DIM 1024
#define OUT_DIM 512
#define RNK 32
#define TG_N 32
#define TGK_N 128
#define AWCOLS 4096
#define KD 4224          // 4096 affine_w cols + 128 bias-indicator cols
#define NKT 66           // KD / 64
#define SCALE_F 0.17677669529663687f

typedef __attribute__((ext_vector_type(8))) short short8;
typedef __attribute__((ext_vector_type(4))) float float4v;

__device__ __forceinline__ unsigned short f2bf(float f) {
  union { float f; unsigned int u; } c; c.f = f;
  unsigned int u = c.u;
  u += 0x7fffu + ((u >> 16) & 1u);   // round-to-nearest-even
  return (unsigned short)(u >> 16);
}

// k_w2t: 32x32 transpose tiles of [affine_w ; affine_b] -> bf16 W2t (O x KD).
// Loads coalesced 128B rows; stores packed bf16x8 (16 B per lane).
__global__ __launch_bounds__(256) void k_w2t(
    const float* __restrict__ aw, const float* __restrict__ ab,
    unsigned short* __restrict__ w2t) {
  __shared__ float tile[32][33];
  const int c0 = blockIdx.x * 32, o0 = blockIdx.y * 32;
  const int t = threadIdx.x;
  const int oo = t & 31, cc = t >> 5;  // cc 0..7
#pragma unroll
  for (int p = 0; p < 4; ++p) {
    int cidx = c0 + cc + p * 8;
    float v = (cidx < AWCOLS)
                  ? aw[(size_t)cidx * OUT_DIM + o0 + oo]
                  : ab[(size_t)(cidx - AWCOLS) * OUT_DIM + o0 + oo];
    tile[cc + p * 8][oo] = v;
  }
  __syncthreads();
  if (t < 128) {
    const int ol = t >> 2, ch = t & 3;  // 32 o-rows x 4 chunks of 8 cols
    union { short8 v; unsigned short u[8]; } pk;
#pragma unroll
    for (int j = 0; j < 8; ++j) pk.u[j] = f2bf(tile[ch * 8 + j][ol]);
    *(short8*)(w2t + (size_t)(o0 + ol) * KD + c0 + ch * 8) = pk.v;
  }
}

// k_zwin: 2 tokens/block. z in fp32 (same summation order as the passing R1/R2
// versions -- winner selection must stay bit-stable), then bf16 z + packed winners.
__global__ __launch_bounds__(256) void k_zwin(
    const float* __restrict__ x, const float* __restrict__ proj_w,
    const float* __restrict__ router_w, const float* __restrict__ router_b,
    unsigned short* __restrict__ zout, unsigned long long* __restrict__ wout) {
  const int tok2 = blockIdx.x * 2;
  const int t = threadIdx.x;
  __shared__ __align__(16) float zbuf[2][RNK];
  __shared__ float sc[2][TGK_N];
  __shared__ int winbuf[2][TG_N];

  const int r = t >> 3, c = t & 7;
  const float4* w4 = (const float4*)(proj_w + (size_t)r * IN_DIM);
  const float4* x0 = (const float4*)(x + (size_t)tok2 * IN_DIM);
  float a0 = 0.f, a1 = 0.f;
#pragma unroll
  for (int jj = 0; jj < 32; ++jj) {
    float4 wv = w4[jj * 8 + c];
    float4 xv0 = x0[jj * 8 + c];
    float4 xv1 = x0[256 + jj * 8 + c];
    a0 += xv0.x * wv.x + xv0.y * wv.y + xv0.z * wv.z + xv0.w * wv.w;
    a1 += xv1.x * wv.x + xv1.y * wv.y + xv1.z * wv.z + xv1.w * wv.w;
  }
  a0 += __shfl_xor(a0, 1); a0 += __shfl_xor(a0, 2); a0 += __shfl_xor(a0, 4);
  a1 += __shfl_xor(a1, 1); a1 += __shfl_xor(a1, 2); a1 += __shfl_xor(a1, 4);
  if (c == 0) { zbuf[0][r] = a0; zbuf[1][r] = a1; }
  __syncthreads();

  {  // thread -> (token = t>>7, cell = t&127)
    const int cell = t & 127, tk = t >> 7;
    const float4* rw = (const float4*)(router_w + (size_t)cell * RNK);
    const float4* zb = (const float4*)(&zbuf[tk][0]);
    float s = router_b[cell];
#pragma unroll
    for (int j = 0; j < 8; ++j) {
      float4 a = rw[j]; float4 b = zb[j];
      s += a.x * b.x + a.y * b.y + a.z * b.z + a.w * b.w;
    }
    sc[tk][cell] = s;
  }
  __syncthreads();

  if (t < 64) {
    const int tk = t >> 5, tg = t & 31;
    float best = sc[tk][tg * 4]; int w = 0;
#pragma unroll
    for (int k = 1; k < 4; ++k) {
      float v = sc[tk][tg * 4 + k];
      if (v < best) { best = v; w = k; }
    }
    winbuf[tk][tg] = w;
    zout[(size_t)(tok2 + tk) * RNK + tg] = f2bf(zbuf[tk][tg]);  // tg doubles as r
  }
  __syncthreads();
  if (t < 2) {
    unsigned long long w = 0ull;
    for (int g = 0; g < TG_N; ++g)
      w |= ((unsigned long long)(winbuf[t][g] & 3)) << (2 * g);
    wout[tok2 + t] = w;
  }
}

// k_gemm v3: out = Zexp @ W2t^T. A (z + winner bits) register-resident, zero
// traffic. B staged through an 8-deep LDS ring via global_load_lds (16 B/lane),
// AITER-style: s_waitcnt vmcnt(6) (never drains) + raw s_barrier; issue of
// kt+7 AFTER the barrier makes slot reuse ordered, not timing-dependent.
// 64M x 32N per block, 4 waves (2M x 2N), grid 32x16 = 512 blocks = 2/CU.
__global__ __launch_bounds__(256) void k_gemm(
    const unsigned short* __restrict__ z, const unsigned long long* __restrict__ win,
    const unsigned short* __restrict__ Bt, float* __restrict__ out) {
  __shared__ __align__(16) unsigned short Bs[8][2048];  // 8 slots x 4 KB
  const int bm = blockIdx.x, bn = blockIdx.y;
  const int tid = threadIdx.x;
  const int wave = tid >> 6, lane = tid & 63;
  const int l15 = lane & 15, quad = lane >> 4;
  const int mw = (wave & 1) * 32;
  const int nw = (wave >> 1) * 16;

  const int m0 = bm * 64 + mw + l15;
  const int m1 = m0 + 16;
  short8 z0 = *(const short8*)(z + (size_t)m0 * RNK + quad * 8);
  short8 z1 = *(const short8*)(z + (size_t)m1 * RNK + quad * 8);
  const unsigned long long w0 = win[m0], w1 = win[m1];

  // staging: thread -> (n = tid>>3, cpos = tid&7); source chunk XOR-swizzled
  const int sn = tid >> 3;
  const unsigned short* bsrc =
      Bt + (size_t)(bn * 32 + sn) * KD + (((tid & 7) ^ (sn & 7)) * 8);

  const int fn = nw + l15;  // B row (n) this lane's frags come from
  float4v acc0 = {}, acc1 = {};

#define ISSUE(KT)                                                              \
  __builtin_amdgcn_global_load_lds(                                            \
      (const __attribute__((address_space(1))) void*)(bsrc + (size_t)(KT) * 64), \
      (__attribute__((address_space(3))) void*)(&Bs[(KT) & 7][wave * 512]),    \
      16, 0, 0)

  auto compute = [&](int kt) __attribute__((always_inline)) {
    const unsigned short* sb = &Bs[kt & 7][0];
    if (kt < 64) {
      const int tg = kt >> 1;
      const unsigned e0 = (unsigned)(w0 >> (2 * tg)) & 3u;
      const unsigned e1 = (unsigned)(w1 >> (2 * tg)) & 3u;
#pragma unroll
      for (int s = 0; s < 2; ++s) {
        const unsigned kk = (unsigned)(((kt & 1) << 1) | s);
        short8 zz = {};
        short8 b = *(const short8*)(sb + fn * 64 + (((s * 4 + quad) ^ (fn & 7)) * 8));
        acc0 = __builtin_amdgcn_mfma_f32_16x16x32_bf16(e0 == kk ? z0 : zz, b, acc0, 0, 0, 0);
        acc1 = __builtin_amdgcn_mfma_f32_16x16x32_bf16(e1 == kk ? z1 : zz, b, acc1, 0, 0, 0);
      }
    } else {
      // bias-indicator tiles: one-hot bf16(1.0) at winner cell (same as R2, passed)
#pragma unroll
      for (int s = 0; s < 2; ++s) {
        const int tgA = (kt - 64) * 16 + s * 8 + quad * 2;  // <= 30
        union { short8 v; unsigned long long q[2]; } fa, fb;
        fa.q[0] = 0x3F80ull << (((unsigned)(w0 >> (2 * tgA)) & 3u) * 16);
        fa.q[1] = 0x3F80ull << (((unsigned)(w0 >> (2 * (tgA + 1))) & 3u) * 16);
        fb.q[0] = 0x3F80ull << (((unsigned)(w1 >> (2 * tgA)) & 3u) * 16);
        fb.q[1] = 0x3F80ull << (((unsigned)(w1 >> (2 * (tgA + 1))) & 3u) * 16);
        short8 b = *(const short8*)(sb + fn * 64 + (((s * 4 + quad) ^ (fn & 7)) * 8));
        acc0 = __builtin_amdgcn_mfma_f32_16x16x32_bf16(fa.v, b, acc0, 0, 0, 0);
        acc1 = __builtin_amdgcn_mfma_f32_16x16x32_bf16(fb.v, b, acc1, 0, 0, 0);
      }
    }
  };

  ISSUE(0); ISSUE(1); ISSUE(2); ISSUE(3); ISSUE(4); ISSUE(5); ISSUE(6);

  for (int kt = 0; kt < 60; ++kt) {
    asm volatile("s_waitcnt vmcnt(6)" ::: "memory");  // slot kt landed; 6 in flight
    asm volatile("s_barrier" ::: "memory");           // everyone past compute(kt-1)
    if (kt <= 58) ISSUE(kt + 7);                      // overwrites slot of kt-1: safe
    compute(kt);
  }
  asm volatile("s_waitcnt vmcnt(5)" ::: "memory"); asm volatile("s_barrier" ::: "memory"); compute(60);
  asm volatile("s_waitcnt vmcnt(4)" ::: "memory"); asm volatile("s_barrier" ::: "memory"); compute(61);
  asm volatile("s_waitcnt vmcnt(3)" ::: "memory"); asm volatile("s_barrier" ::: "memory"); compute(62);
  asm volatile("s_waitcnt vmcnt(2)" ::: "memory"); asm volatile("s_barrier" ::: "memory"); compute(63);
  asm volatile("s_waitcnt vmcnt(1)" ::: "memory"); asm volatile("s_barrier" ::: "memory"); compute(64);
  asm volatile("s_waitcnt vmcnt(0)" ::: "memory"); asm volatile("s_barrier" ::: "memory"); compute(65);
#undef ISSUE

  // epilogue: C/D layout col = lane&15, row = quad*4 + reg
  const int col = bn * 32 + nw + l15;
#pragma unroll
  for (int tm = 0; tm < 2; ++tm) {
    float4v a = tm ? acc1 : acc0;
    const int rowb = bm * 64 + mw + tm * 16 + quad * 4;
#pragma unroll
    for (int rg = 0; rg < 4; ++rg)
      out[(size_t)(rowb + rg) * OUT_DIM + col] = a[rg] * SCALE_F;
  }
}

extern "C" void kernel_launch(void* const* d_in, const int* in_sizes, int n_in,
                              void* d_out, int out_size, void* d_ws, size_t ws_size,
                              hipStream_t stream) {
  const float* x        = (const float*)d_in[0];
  const float* proj_w   = (const float*)d_in[1];
  const float* router_w = (const float*)d_in[2];
  const float* router_b = (const float*)d_in[3];
  const float* affine_w = (const float*)d_in[4];
  const float* affine_b = (const float*)d_in[5];
  float* out = (float*)d_out;

  unsigned short* zout = (unsigned short*)d_ws;                            // 128 KB
  unsigned long long* wout = (unsigned long long*)((char*)d_ws + 131072);  // 16 KB
  unsigned short* w2t = (unsigned short*)((char*)d_ws + 147456);           // 4.33 MB

  k_w2t<<<dim3(KD / 32, OUT_DIM / 32), 256, 0, stream>>>(affine_w, affine_b, w2t);
  k_zwin<<<NTOK / 2, 256, 0, stream>>>(x, proj_w, router_w, router_b, zout, wout);
  k_gemm<<<dim3(NTOK / 64, OUT_DIM / 32), 256, 0, stream>>>(zout, wout, w2t, out);
}